// Round 8
// baseline (7642.506 us; speedup 1.0000x reference)
//
#include <hip/hip_runtime.h>
#include <math.h>

// LatentSDE (L=C=D=1, H=64): all nets tabulated (f(z,c) bilinear 2D).
// Thread-per-b scalar recurrence (no cross-lane ops). R7 lesson: with only
// 128 waves there is NO TLP -> every on-chain table must live in LDS
// (gather latency ~120cy) instead of global (serialized miss latency).
// Tables: f c-pairs z[-24,24]x c[-2,2] (48KB), hgp float4 (3KB),
// enc x-pairs (8KB) -> ~59KB LDS/block, 32 blocks x 256 thr.
// OOB z/c -> exact per-lane MLP fallback from global weights (rare, exact).
// Fused deterministic reduction via atomic counter (R7-verified pattern).

#define B_SZ 8192
#define T_SZ 128
#define NBLK 32

#define NZI 192                  // z intervals, z in [-24,24], dz=1/4
#define ZSF 4.0f
#define ZOF 96.0f
#define NCI 32                   // c intervals, c in [-2,2], dc=1/8
#define CSF 8.0f
#define COF 16.0f
#define NXI 1024                 // x intervals, x in [-8,8], dx=1/64
#define XSF 64.0f
#define XOF 512.0f

// table layout in floats (float4-aligned sections)
#define ET2_OFF 0                            // 1024 float2 = 2048
#define HGP_OFF 2048                         // 193 float4  = 772
#define FT2_OFF 2820                         // 193*32 float2 = 12352
#define TAB_FLOATS 15172                     // total (divisible by 4)

#define NE_BUILD 1024
#define NH_BUILD 193
#define NF_BUILD (193*32)
#define NBUILD (NE_BUILD + NH_BUILD + NF_BUILD)   // 7393

#if __has_builtin(__builtin_amdgcn_rcpf)
#define RCPF(x) __builtin_amdgcn_rcpf(x)
#else
#define RCPF(x) (1.0f / (x))
#endif
#if __has_builtin(__builtin_amdgcn_sqrtf)
#define SQRTF(x) __builtin_amdgcn_sqrtf(x)
#else
#define SQRTF(x) sqrtf(x)
#endif

__device__ __forceinline__ float sp_precise(float a) {
  return fmaxf(a, 0.0f) + log1pf(expf(-fabsf(a)));
}

// ---------------- build: exact 64-unit evals into global tables ----------------
__global__ __launch_bounds__(256) void build_tabs(
    const float* __restrict__ ew1, const float* __restrict__ eb1,
    const float* __restrict__ ew2, const float* __restrict__ eb2,
    const float* __restrict__ fw1, const float* __restrict__ fb1,
    const float* __restrict__ fw2, const float* __restrict__ fb2,
    const float* __restrict__ hw1, const float* __restrict__ hb1,
    const float* __restrict__ hw2, const float* __restrict__ hb2,
    const float* __restrict__ gw1, const float* __restrict__ gb1,
    const float* __restrict__ gw2, const float* __restrict__ gb2,
    const float* __restrict__ pw1, const float* __restrict__ pb1,
    const float* __restrict__ pw2, const float* __restrict__ pb2,
    float* __restrict__ tabs, int* __restrict__ ctr)
{
  const int gid = blockIdx.x * 256 + threadIdx.x;
  if (gid == 0) *ctr = 0;

  if (gid < NE_BUILD) {
    const float x0 = -8.0f + (float)gid * (1.0f / 64.0f);
    const float x1 = x0 + (1.0f / 64.0f);
    float s0 = 0.0f, s1 = 0.0f;
    for (int j = 0; j < 64; ++j) {
      const float w = ew1[j], bb = eb1[j], w2 = ew2[j];
      s0 = fmaf(sp_precise(fmaf(x0, w, bb)), w2, s0);
      s1 = fmaf(sp_precise(fmaf(x1, w, bb)), w2, s1);
    }
    const float eb = eb2[0];
    ((float2*)(tabs + ET2_OFF))[gid] = make_float2(s0 + eb, s1 + eb);
  } else if (gid < NE_BUILD + NH_BUILD) {
    const int i = gid - NE_BUILD;
    const float z = -24.0f + (float)i * 0.25f;
    float sh = 0.0f, sg = 0.0f, sp = 0.0f;
    for (int j = 0; j < 64; ++j) {
      sh = fmaf(sp_precise(fmaf(z, hw1[j], hb1[j])), hw2[j], sh);
      sg = fmaf(sp_precise(fmaf(z, gw1[j], gb1[j])), gw2[j], sg);
      sp = fmaf(sp_precise(fmaf(z, pw1[j], pb1[j])), pw2[j], sp);
    }
    ((float4*)(tabs + HGP_OFF))[i] = make_float4(
        sh + hb2[0],
        1.0f / (1.0f + expf(-(sg + gb2[0]))),
        sp + pb2[0], 0.0f);
  } else if (gid < NBUILD) {
    const int fi = gid - NE_BUILD - NH_BUILD;
    const int iz = fi >> 5;
    const int ci = fi & 31;
    const float z  = -24.0f + (float)iz * 0.25f;
    const float c0 = -2.0f + (float)ci * 0.125f;
    const float c1 = c0 + 0.125f;
    float s0 = 0.0f, s1 = 0.0f;
    for (int j = 0; j < 64; ++j) {
      const float az = fmaf(z, fw1[j], fb1[j]);
      const float wc = fw1[64 + j], w2 = fw2[j];
      s0 = fmaf(sp_precise(fmaf(c0, wc, az)), w2, s0);
      s1 = fmaf(sp_precise(fmaf(c1, wc, az)), w2, s1);
    }
    const float fb = fb2[0];
    ((float2*)(tabs + FT2_OFF))[iz * NCI + ci] = make_float2(s0 + fb, s1 + fb);
  }
}

// ---------------- scan: thread-per-b, LDS tables, fused reduction ----------------
__global__ __launch_bounds__(256) void sde_scan(
    const float* __restrict__ xs, const float* __restrict__ ts,
    const float* __restrict__ noise_std, const float* __restrict__ eps0,
    const float* __restrict__ dW,
    const float* __restrict__ qw,  const float* __restrict__ qb,
    const float* __restrict__ fw1, const float* __restrict__ fb1,
    const float* __restrict__ fw2, const float* __restrict__ fb2,
    const float* __restrict__ hw1, const float* __restrict__ hb1,
    const float* __restrict__ hw2, const float* __restrict__ hb2,
    const float* __restrict__ gw1, const float* __restrict__ gb1,
    const float* __restrict__ gw2, const float* __restrict__ gb2,
    const float* __restrict__ pw1, const float* __restrict__ pb1,
    const float* __restrict__ pw2, const float* __restrict__ pb2,
    const float* __restrict__ pz0_mean, const float* __restrict__ pz0_logstd,
    const float* __restrict__ tabsrc,
    int* __restrict__ ctr, float* __restrict__ partA, float* __restrict__ partB,
    float* __restrict__ out)
{
  __shared__ __align__(16) float tab[TAB_FLOATS];
  __shared__ float la[256], lb[256];
  __shared__ int lastflag;

  const int tid = threadIdx.x;
  const int b   = blockIdx.x * 256 + tid;

  // stage all tables into LDS (float4-wise)
  {
    const float4* s4 = (const float4*)tabsrc;
    float4* d4 = (float4*)tab;
    for (int i = tid; i < TAB_FLOATS / 4; i += 256) d4[i] = s4[i];
  }
  __syncthreads();

  const float2* et2  = (const float2*)(tab + ET2_OFF);
  const float4* hgp4 = (const float4*)(tab + HGP_OFF);
  const float2* ft2  = (const float2*)(tab + FT2_OFF);

  const float fb2s = fb2[0], hb2s = hb2[0], gb2s = gb2[0], pb2s = pb2[0];
  const float qw0 = qw[0], qw1 = qw[1], qb0 = qb[0], qb1 = qb[1];
  const float ns = noise_std[0];
  const float inv_ns = 1.0f / ns;
  const float nh_i2 = -0.5f * inv_ns * inv_ns;
  const float pm = pz0_mean[0], pls = pz0_logstd[0];

  auto einterp = [&](float x) {
    const float s = fmaf(x, XSF, XOF);
    const float sc = fminf(fmaxf(s, 0.0f), (float)(NXI - 1));
    const int i = (int)sc;
    const float fr = s - (float)i;
    const float2 e = et2[i];
    return fmaf(fr, e.y - e.x, e.x);
  };
  auto hgp_exact = [&](float z, float& hv, float& gv, float& pv) {
    float sh = 0.f, sg = 0.f, sp = 0.f;
    for (int j = 0; j < 64; ++j) {
      sh = fmaf(sp_precise(fmaf(z, hw1[j], hb1[j])), hw2[j], sh);
      sg = fmaf(sp_precise(fmaf(z, gw1[j], gb1[j])), gw2[j], sg);
      sp = fmaf(sp_precise(fmaf(z, pw1[j], pb1[j])), pw2[j], sp);
    }
    hv = sh + hb2s;
    gv = 1.0f / (1.0f + expf(-(sg + gb2s)));
    pv = sp + pb2s;
  };
  auto f_exact = [&](float z, float c) {
    float s = 0.f;
    for (int j = 0; j < 64; ++j)
      s = fmaf(sp_precise(fmaf(z, fw1[j], fmaf(c, fw1[64 + j], fb1[j]))), fw2[j], s);
    return s + fb2s;
  };

  // z-grid state
  int zi; float zf; bool zin;
  auto setz = [&](float z) {
    const float s = fmaf(z, ZSF, ZOF);
    zin = (s >= 0.0f) && (s <= (float)NZI);
    const float sc = fminf(fmaxf(s, 0.0f), (float)(NZI - 1));
    zi = (int)sc;
    zf = s - (float)zi;
  };

  // ---- prologue ----
  const float x0 = xs[b];
  float x1 = xs[B_SZ + b];
  float x2 = xs[2 * B_SZ + b];
  const float c0v = einterp(x0);
  float c_cur = einterp(x1);
  float c_nxt = einterp(x2);
  const float qm  = fmaf(c0v, qw0, qb0);
  const float qls = fmaf(c0v, qw1, qb1);
  float z = fmaf(__expf(qls), eps0[b], qm);
  const float dqm = qm - pm;
  const float kl = (pls - qls)
                 + (__expf(2.0f * qls) + dqm * dqm) * (0.5f * __expf(-2.0f * pls))
                 - 0.5f;

  setz(z);
  float hv, gv, pv;
  if (zin) {
    const float4 a = hgp4[zi], bq = hgp4[zi + 1];
    hv = fmaf(zf, bq.x - a.x, a.x);
    gv = fmaf(zf, bq.y - a.y, a.y);
    pv = fmaf(zf, bq.z - a.z, a.z);
  } else {
    hgp_exact(z, hv, gv, pv);
  }
  float lp_sum; { const float d = x0 - pv; lp_sum = nh_i2 * d * d; }
  float lr_sum = 0.0f;
  float dw_cur = dW[b];

  // prefetch f-rows for step 0
  float csx = fmaf(c_cur, CSF, COF);
  bool  cin = (csx >= 0.0f) && (csx <= (float)NCI);
  float cc  = fminf(fmaxf(csx, 0.0f), (float)(NCI - 1));
  int   ci  = (int)cc;
  float cfr = csx - (float)ci;
  float2 r0 = ft2[zi * NCI + ci];
  float2 r1 = ft2[(zi + 1) * NCI + ci];

  // ---- Euler-Maruyama scan ----
  for (int k = 0; k < T_SZ - 1; ++k) {
    const int   i3  = (k + 3 < T_SZ) ? (k + 3) : (T_SZ - 1);
    const float x3  = xs[i3 * B_SZ + b];
    const float dwn = (k + 1 < T_SZ - 1) ? dW[(k + 1) * B_SZ + b] : 0.0f;
    const float dt  = ts[k + 1] - ts[k];
    const float sq  = SQRTF(dt);

    // f(z, c_cur) from prefetched rows (bilinear) or exact fallback
    float fv;
    if (zin && cin) {
      const float fa  = fmaf(cfr, r0.y - r0.x, r0.x);
      const float fbv = fmaf(cfr, r1.y - r1.x, r1.x);
      fv = fmaf(zf, fbv - fa, fa);
    } else {
      fv = f_exact(z, c_cur);
    }

    const float uu = (fv - hv) * RCPF(gv);
    lr_sum = fmaf((0.5f * dt) * uu, uu, lr_sum);
    z = fmaf(gv * dw_cur, sq, fmaf(fv, dt, z));

    // h,g (next step) + p (lp now) at new z
    setz(z);
    if (zin) {
      const float4 a = hgp4[zi], bq = hgp4[zi + 1];
      hv = fmaf(zf, bq.x - a.x, a.x);
      gv = fmaf(zf, bq.y - a.y, a.y);
      pv = fmaf(zf, bq.z - a.z, a.z);
    } else {
      hgp_exact(z, hv, gv, pv);
    }
    const float d = x1 - pv;
    lp_sum = fmaf(nh_i2 * d, d, lp_sum);

    // advance c pipeline; prefetch f-rows for next step
    c_cur = c_nxt;
    csx = fmaf(c_cur, CSF, COF);
    cin = (csx >= 0.0f) && (csx <= (float)NCI);
    cc  = fminf(fmaxf(csx, 0.0f), (float)(NCI - 1));
    ci  = (int)cc;
    cfr = csx - (float)ci;
    r0 = ft2[zi * NCI + ci];
    r1 = ft2[(zi + 1) * NCI + ci];
    c_nxt = einterp(x3);
    x1 = x2; x2 = x3;
    dw_cur = dwn;
  }

  // ---- fused deterministic reduction ----
  la[tid] = lp_sum; lb[tid] = kl + lr_sum;
  __syncthreads();
  for (int s = 128; s > 0; s >>= 1) {
    if (tid < s) { la[tid] += la[tid + s]; lb[tid] += lb[tid + s]; }
    __syncthreads();
  }
  if (tid == 0) {
    partA[blockIdx.x] = la[0]; partB[blockIdx.x] = lb[0];
    __threadfence();
    lastflag = (atomicAdd(ctr, 1) == NBLK - 1) ? 1 : 0;
  }
  __syncthreads();
  if (lastflag) {
    __threadfence();
    la[tid] = (tid < NBLK) ? partA[tid] : 0.0f;
    lb[tid] = (tid < NBLK) ? partB[tid] : 0.0f;
    __syncthreads();
    for (int s = 128; s > 0; s >>= 1) {
      if (tid < s) { la[tid] += la[tid + s]; lb[tid] += lb[tid + s]; }
      __syncthreads();
    }
    if (tid == 0) {
      out[0] = la[0] / (float)B_SZ
             + (float)T_SZ * (-__logf(ns) - 0.9189385332046727f);
      out[1] = lb[0] / (float)B_SZ;
    }
  }
}

extern "C" void kernel_launch(void* const* d_in, const int* in_sizes, int n_in,
                              void* d_out, int out_size, void* d_ws, size_t ws_size,
                              hipStream_t stream) {
  const float* xs        = (const float*)d_in[0];
  const float* ts        = (const float*)d_in[1];
  const float* noise_std = (const float*)d_in[2];
  const float* eps0      = (const float*)d_in[3];
  const float* dW        = (const float*)d_in[4];
  const float* ew1 = (const float*)d_in[5];
  const float* eb1 = (const float*)d_in[6];
  const float* ew2 = (const float*)d_in[7];
  const float* eb2 = (const float*)d_in[8];
  const float* qw  = (const float*)d_in[9];
  const float* qb  = (const float*)d_in[10];
  const float* fw1 = (const float*)d_in[11];
  const float* fb1 = (const float*)d_in[12];
  const float* fw2 = (const float*)d_in[13];
  const float* fb2 = (const float*)d_in[14];
  const float* hw1 = (const float*)d_in[15];
  const float* hb1 = (const float*)d_in[16];
  const float* hw2 = (const float*)d_in[17];
  const float* hb2 = (const float*)d_in[18];
  const float* gw1 = (const float*)d_in[19];
  const float* gb1 = (const float*)d_in[20];
  const float* gw2 = (const float*)d_in[21];
  const float* gb2 = (const float*)d_in[22];
  const float* pw1 = (const float*)d_in[23];
  const float* pb1 = (const float*)d_in[24];
  const float* pw2 = (const float*)d_in[25];
  const float* pb2 = (const float*)d_in[26];
  const float* pz0_mean   = (const float*)d_in[27];
  const float* pz0_logstd = (const float*)d_in[28];
  float* out = (float*)d_out;

  float* tabs  = (float*)d_ws;                  // [TAB_FLOATS]
  int*   ctr   = (int*)(tabs + TAB_FLOATS);     // [1] (+pad)
  float* partA = tabs + TAB_FLOATS + 4;         // [NBLK]
  float* partB = partA + NBLK;                  // [NBLK]

  build_tabs<<<(NBUILD + 255) / 256, 256, 0, stream>>>(
      ew1, eb1, ew2, eb2, fw1, fb1, fw2, fb2,
      hw1, hb1, hw2, hb2, gw1, gb1, gw2, gb2,
      pw1, pb1, pw2, pb2, tabs, ctr);

  sde_scan<<<NBLK, 256, 0, stream>>>(
      xs, ts, noise_std, eps0, dW, qw, qb,
      fw1, fb1, fw2, fb2, hw1, hb1, hw2, hb2,
      gw1, gb1, gw2, gb2, pw1, pb1, pw2, pb2,
      pz0_mean, pz0_logstd, tabs, ctr, partA, partB, out);
}

// Round 9
// 3202.184 us; speedup vs baseline: 2.3867x; 2.3867x over previous
//
#include <hip/hip_runtime.h>
#include <math.h>

// LatentSDE (L=C=D=1, H=64), all nets tabulated, thread-per-b recurrence.
// R8 lesson: z escapes +-24 constantly (multiplicative drift; R5 proved +-64
// insufficient) -> exact-MLP fallback fired nearly every wave-step = 60%
// VALU-busy on 32 CUs. Fix: cover z in [-128,128] (R7-verified) and compress
// the c-dimension analytically: f(z,c) tabulated at 4 Lagrange c-nodes
// {-3,-1,1,3} (cubic-in-c, err ~1e-5; c is the tiny encoder output).
// LDS: fq4 2049*16B (32.8K) + hgp4 1025*16B (16.4K) + enc 1024*8B (8K)
// = 57.4KB -> 64-thr blocks x 128 -> 128 CUs, ~200cy/step latency chain.

#define B_SZ 8192
#define T_SZ 128
#define NBLK 128

// f-table: z in [-128,128], dz=1/8 -> 2048 intervals, 2049 float4 entries
#define NZF 2048
#define ZSF_F 8.0f
#define ZOF_F 1024.0f
// hgp-table: z in [-128,128], dz=1/4 -> 1024 intervals, 1025 float4 entries
#define NZH 1024
#define ZSF_H 4.0f
#define ZOF_H 512.0f
// enc-table: x in [-8,8], dx=1/64 -> 1024 pairs (linear extrapolation OOB)
#define NXI 1024
#define XSF 64.0f
#define XOF 512.0f

// float offsets (all float4-aligned)
#define FQ_OFF  0                 // 2049*4 = 8196
#define HGP_OFF 8196              // 1025*4 = 4100
#define ET2_OFF 12296             // 1024*2 = 2048
#define TAB_FLOATS 14344          // 57,376 B

#define NF_BUILD 2049
#define NH_BUILD 1025
#define NE_BUILD 1024
#define NBUILD (NF_BUILD + NH_BUILD + NE_BUILD)   // 4098

#if __has_builtin(__builtin_amdgcn_rcpf)
#define RCPF(x) __builtin_amdgcn_rcpf(x)
#else
#define RCPF(x) (1.0f / (x))
#endif
#if __has_builtin(__builtin_amdgcn_sqrtf)
#define SQRTF(x) __builtin_amdgcn_sqrtf(x)
#else
#define SQRTF(x) sqrtf(x)
#endif

__device__ __forceinline__ float sp_precise(float a) {
  return fmaxf(a, 0.0f) + log1pf(expf(-fabsf(a)));
}

// ---------------- build: exact evals into global tables ----------------
__global__ __launch_bounds__(256) void build_tabs(
    const float* __restrict__ ew1, const float* __restrict__ eb1,
    const float* __restrict__ ew2, const float* __restrict__ eb2,
    const float* __restrict__ fw1, const float* __restrict__ fb1,
    const float* __restrict__ fw2, const float* __restrict__ fb2,
    const float* __restrict__ hw1, const float* __restrict__ hb1,
    const float* __restrict__ hw2, const float* __restrict__ hb2,
    const float* __restrict__ gw1, const float* __restrict__ gb1,
    const float* __restrict__ gw2, const float* __restrict__ gb2,
    const float* __restrict__ pw1, const float* __restrict__ pb1,
    const float* __restrict__ pw2, const float* __restrict__ pb2,
    float* __restrict__ tabs, int* __restrict__ ctr)
{
  const int gid = blockIdx.x * 256 + threadIdx.x;
  if (gid == 0) *ctr = 0;

  if (gid < NF_BUILD) {
    // f at 4 c-nodes {-3,-1,1,3}
    const float z = -128.0f + (float)gid * 0.125f;
    float s0 = 0.f, s1 = 0.f, s2 = 0.f, s3 = 0.f;
    for (int j = 0; j < 64; ++j) {
      const float az = fmaf(z, fw1[j], fb1[j]);
      const float wc = fw1[64 + j], w2 = fw2[j];
      s0 = fmaf(sp_precise(fmaf(-3.0f, wc, az)), w2, s0);
      s1 = fmaf(sp_precise(fmaf(-1.0f, wc, az)), w2, s1);
      s2 = fmaf(sp_precise(fmaf( 1.0f, wc, az)), w2, s2);
      s3 = fmaf(sp_precise(fmaf( 3.0f, wc, az)), w2, s3);
    }
    const float fb = fb2[0];
    ((float4*)(tabs + FQ_OFF))[gid] =
        make_float4(s0 + fb, s1 + fb, s2 + fb, s3 + fb);
  } else if (gid < NF_BUILD + NH_BUILD) {
    const int i = gid - NF_BUILD;
    const float z = -128.0f + (float)i * 0.25f;
    float sh = 0.f, sg = 0.f, sp = 0.f;
    for (int j = 0; j < 64; ++j) {
      sh = fmaf(sp_precise(fmaf(z, hw1[j], hb1[j])), hw2[j], sh);
      sg = fmaf(sp_precise(fmaf(z, gw1[j], gb1[j])), gw2[j], sg);
      sp = fmaf(sp_precise(fmaf(z, pw1[j], pb1[j])), pw2[j], sp);
    }
    ((float4*)(tabs + HGP_OFF))[i] = make_float4(
        sh + hb2[0],
        1.0f / (1.0f + expf(-(sg + gb2[0]))),
        sp + pb2[0], 0.0f);
  } else if (gid < NBUILD) {
    const int i = gid - NF_BUILD - NH_BUILD;
    const float x0 = -8.0f + (float)i * (1.0f / 64.0f);
    const float x1 = x0 + (1.0f / 64.0f);
    float s0 = 0.f, s1 = 0.f;
    for (int j = 0; j < 64; ++j) {
      const float w = ew1[j], bb = eb1[j], w2 = ew2[j];
      s0 = fmaf(sp_precise(fmaf(x0, w, bb)), w2, s0);
      s1 = fmaf(sp_precise(fmaf(x1, w, bb)), w2, s1);
    }
    const float eb = eb2[0];
    ((float2*)(tabs + ET2_OFF))[i] = make_float2(s0 + eb, s1 + eb);
  }
}

// ---------------- scan: thread-per-b, LDS tables, fused reduction ----------------
__global__ __launch_bounds__(64) void sde_scan(
    const float* __restrict__ xs, const float* __restrict__ ts,
    const float* __restrict__ noise_std, const float* __restrict__ eps0,
    const float* __restrict__ dW,
    const float* __restrict__ qw,  const float* __restrict__ qb,
    const float* __restrict__ fw1, const float* __restrict__ fb1,
    const float* __restrict__ fw2, const float* __restrict__ fb2,
    const float* __restrict__ hw1, const float* __restrict__ hb1,
    const float* __restrict__ hw2, const float* __restrict__ hb2,
    const float* __restrict__ gw1, const float* __restrict__ gb1,
    const float* __restrict__ gw2, const float* __restrict__ gb2,
    const float* __restrict__ pw1, const float* __restrict__ pb1,
    const float* __restrict__ pw2, const float* __restrict__ pb2,
    const float* __restrict__ pz0_mean, const float* __restrict__ pz0_logstd,
    const float* __restrict__ tabsrc,
    int* __restrict__ ctr, float* __restrict__ partA, float* __restrict__ partB,
    float* __restrict__ out)
{
  __shared__ __align__(16) float tab[TAB_FLOATS];
  __shared__ float la[64], lb[64];
  __shared__ int lastflag;

  const int tid = threadIdx.x;
  const int b   = blockIdx.x * 64 + tid;

  { // stage tables (float4-wise)
    const float4* s4 = (const float4*)tabsrc;
    float4* d4 = (float4*)tab;
    for (int i = tid; i < TAB_FLOATS / 4; i += 64) d4[i] = s4[i];
  }
  __syncthreads();

  const float4* fq4  = (const float4*)(tab + FQ_OFF);
  const float4* hgp4 = (const float4*)(tab + HGP_OFF);
  const float2* et2  = (const float2*)(tab + ET2_OFF);

  const float fb2s = fb2[0], hb2s = hb2[0], gb2s = gb2[0], pb2s = pb2[0];
  const float qw0 = qw[0], qw1 = qw[1], qb0 = qb[0], qb1 = qb[1];
  const float ns = noise_std[0];
  const float inv_ns = 1.0f / ns;
  const float nh_i2 = -0.5f * inv_ns * inv_ns;
  const float pm = pz0_mean[0], pls = pz0_logstd[0];

  auto einterp = [&](float x) {   // clamp = linear extrapolation at edges
    const float s = fmaf(x, XSF, XOF);
    const float sc = fminf(fmaxf(s, 0.0f), (float)(NXI - 1));
    const int i = (int)sc;
    const float fr = s - (float)i;
    const float2 e = et2[i];
    return fmaf(fr, e.y - e.x, e.x);
  };
  auto lagr = [&](float c) {      // cubic Lagrange weights, nodes {-3,-1,1,3}
    const float c2 = c * c;
    const float p1 = c2 - 1.0f, p3 = c2 - 9.0f;
    return make_float4(p1 * (c - 3.0f) * (-1.0f / 48.0f),
                       p3 * (c - 1.0f) * ( 1.0f / 16.0f),
                       p3 * (c + 1.0f) * (-1.0f / 16.0f),
                       p1 * (c + 3.0f) * ( 1.0f / 48.0f));
  };
  auto hgp_exact = [&](float z, float& hv, float& gv, float& pv) {
    float sh = 0.f, sg = 0.f, sp = 0.f;
    for (int j = 0; j < 64; ++j) {
      sh = fmaf(sp_precise(fmaf(z, hw1[j], hb1[j])), hw2[j], sh);
      sg = fmaf(sp_precise(fmaf(z, gw1[j], gb1[j])), gw2[j], sg);
      sp = fmaf(sp_precise(fmaf(z, pw1[j], pb1[j])), pw2[j], sp);
    }
    hv = sh + hb2s;
    gv = 1.0f / (1.0f + expf(-(sg + gb2s)));
    pv = sp + pb2s;
  };
  auto f_exact = [&](float z, float c) {
    float s = 0.f;
    for (int j = 0; j < 64; ++j)
      s = fmaf(sp_precise(fmaf(z, fw1[j], fmaf(c, fw1[64 + j], fb1[j]))), fw2[j], s);
    return s + fb2s;
  };

  // ---- prologue ----
  const float x0 = xs[b];
  float x1 = xs[B_SZ + b];
  float x2 = xs[2 * B_SZ + b];
  const float c0v = einterp(x0);
  float c_cur = einterp(x1);
  float c_nxt = einterp(x2);
  const float qm  = fmaf(c0v, qw0, qb0);
  const float qls = fmaf(c0v, qw1, qb1);
  float z = fmaf(__expf(qls), eps0[b], qm);
  const float dqm = qm - pm;
  const float kl = (pls - qls)
                 + (__expf(2.0f * qls) + dqm * dqm) * (0.5f * __expf(-2.0f * pls))
                 - 0.5f;

  // table state at current z
  bool zin; float zff; float4 q0, q1; float hv, gv, pv;
  {
    const float sF = fmaf(z, ZSF_F, ZOF_F);
    zin = (sF >= 0.0f) && (sF <= (float)NZF);
    const float scF = fminf(fmaxf(sF, 0.0f), (float)(NZF - 1));
    const int ziF = (int)scF; zff = sF - (float)ziF;
    const float sH = fmaf(z, ZSF_H, ZOF_H);
    const float scH = fminf(fmaxf(sH, 0.0f), (float)(NZH - 1));
    const int ziH = (int)scH; const float zfh = sH - (float)ziH;
    q0 = fq4[ziF]; q1 = fq4[ziF + 1];
    const float4 a = hgp4[ziH], bq = hgp4[ziH + 1];
    if (zin) {
      hv = fmaf(zfh, bq.x - a.x, a.x);
      gv = fmaf(zfh, bq.y - a.y, a.y);
      pv = fmaf(zfh, bq.z - a.z, a.z);
    } else {
      hgp_exact(z, hv, gv, pv);
    }
  }
  float lp_sum; { const float d = x0 - pv; lp_sum = nh_i2 * d * d; }
  float lr_sum = 0.0f;
  float dw_cur = dW[b];
  float dw_n1  = dW[B_SZ + b];
  float4 L = lagr(c_cur);
  bool cin = fabsf(c_cur) <= 3.0f;

  // ---- Euler-Maruyama scan ----
  for (int k = 0; k < T_SZ - 1; ++k) {
    const int   i3  = (k + 3 < T_SZ) ? (k + 3) : (T_SZ - 1);
    const float x3  = xs[i3 * B_SZ + b];
    const float dw_n2 = (k + 2 < T_SZ - 1) ? dW[(k + 2) * B_SZ + b] : 0.0f;
    const float dt  = ts[k + 1] - ts[k];
    const float sq  = SQRTF(dt);

    // f(z, c_cur): z-lerp of 4 c-node values, then cubic in c
    float fv;
    if (zin && cin) {
      const float n0 = fmaf(zff, q1.x - q0.x, q0.x);
      const float n1 = fmaf(zff, q1.y - q0.y, q0.y);
      const float n2 = fmaf(zff, q1.z - q0.z, q0.z);
      const float n3 = fmaf(zff, q1.w - q0.w, q0.w);
      fv = n0 * L.x + n1 * L.y + n2 * L.z + n3 * L.w;
    } else {
      fv = f_exact(z, c_cur);
    }

    const float gvs = fmaxf(gv, 1e-6f);
    const float uu = (fv - hv) * RCPF(gvs);
    lr_sum = fmaf((0.5f * dt) * uu, uu, lr_sum);
    z = fmaf(gvs * dw_cur, sq, fmaf(fv, dt, z));

    // re-index at new z; issue all 4 table reads together
    const float sF = fmaf(z, ZSF_F, ZOF_F);
    zin = (sF >= 0.0f) && (sF <= (float)NZF);
    const float scF = fminf(fmaxf(sF, 0.0f), (float)(NZF - 1));
    const int ziF = (int)scF; zff = sF - (float)ziF;
    const float sH = fmaf(z, ZSF_H, ZOF_H);
    const float scH = fminf(fmaxf(sH, 0.0f), (float)(NZH - 1));
    const int ziH = (int)scH; const float zfh = sH - (float)ziH;
    q0 = fq4[ziF]; q1 = fq4[ziF + 1];
    const float4 a = hgp4[ziH], bq = hgp4[ziH + 1];
    if (zin) {
      hv = fmaf(zfh, bq.x - a.x, a.x);
      gv = fmaf(zfh, bq.y - a.y, a.y);
      pv = fmaf(zfh, bq.z - a.z, a.z);
    } else {
      hgp_exact(z, hv, gv, pv);
    }

    // projector likelihood at t=k+1
    const float d = x1 - pv;
    lp_sum = fmaf(nh_i2 * d, d, lp_sum);

    // advance pipelines (off-chain)
    c_cur = c_nxt; L = lagr(c_cur); cin = fabsf(c_cur) <= 3.0f;
    c_nxt = einterp(x3);
    x1 = x2; x2 = x3;
    dw_cur = dw_n1; dw_n1 = dw_n2;
  }

  // ---- fused deterministic reduction ----
  la[tid] = lp_sum; lb[tid] = kl + lr_sum;
  __syncthreads();
  for (int s = 32; s > 0; s >>= 1) {
    if (tid < s) { la[tid] += la[tid + s]; lb[tid] += lb[tid + s]; }
    __syncthreads();
  }
  if (tid == 0) {
    partA[blockIdx.x] = la[0]; partB[blockIdx.x] = lb[0];
    __threadfence();
    lastflag = (atomicAdd(ctr, 1) == NBLK - 1) ? 1 : 0;
  }
  __syncthreads();
  if (lastflag) {
    __threadfence();
    la[tid] = partA[tid] + partA[tid + 64];
    lb[tid] = partB[tid] + partB[tid + 64];
    __syncthreads();
    for (int s = 32; s > 0; s >>= 1) {
      if (tid < s) { la[tid] += la[tid + s]; lb[tid] += lb[tid + s]; }
      __syncthreads();
    }
    if (tid == 0) {
      out[0] = la[0] / (float)B_SZ
             + (float)T_SZ * (-__logf(ns) - 0.9189385332046727f);
      out[1] = lb[0] / (float)B_SZ;
    }
  }
}

extern "C" void kernel_launch(void* const* d_in, const int* in_sizes, int n_in,
                              void* d_out, int out_size, void* d_ws, size_t ws_size,
                              hipStream_t stream) {
  const float* xs        = (const float*)d_in[0];
  const float* ts        = (const float*)d_in[1];
  const float* noise_std = (const float*)d_in[2];
  const float* eps0      = (const float*)d_in[3];
  const float* dW        = (const float*)d_in[4];
  const float* ew1 = (const float*)d_in[5];
  const float* eb1 = (const float*)d_in[6];
  const float* ew2 = (const float*)d_in[7];
  const float* eb2 = (const float*)d_in[8];
  const float* qw  = (const float*)d_in[9];
  const float* qb  = (const float*)d_in[10];
  const float* fw1 = (const float*)d_in[11];
  const float* fb1 = (const float*)d_in[12];
  const float* fw2 = (const float*)d_in[13];
  const float* fb2 = (const float*)d_in[14];
  const float* hw1 = (const float*)d_in[15];
  const float* hb1 = (const float*)d_in[16];
  const float* hw2 = (const float*)d_in[17];
  const float* hb2 = (const float*)d_in[18];
  const float* gw1 = (const float*)d_in[19];
  const float* gb1 = (const float*)d_in[20];
  const float* gw2 = (const float*)d_in[21];
  const float* gb2 = (const float*)d_in[22];
  const float* pw1 = (const float*)d_in[23];
  const float* pb1 = (const float*)d_in[24];
  const float* pw2 = (const float*)d_in[25];
  const float* pb2 = (const float*)d_in[26];
  const float* pz0_mean   = (const float*)d_in[27];
  const float* pz0_logstd = (const float*)d_in[28];
  float* out = (float*)d_out;

  float* tabs  = (float*)d_ws;                  // [TAB_FLOATS]
  int*   ctr   = (int*)(tabs + TAB_FLOATS);     // [1] (+pad)
  float* partA = tabs + TAB_FLOATS + 4;         // [NBLK]
  float* partB = partA + NBLK;                  // [NBLK]

  build_tabs<<<(NBUILD + 255) / 256, 256, 0, stream>>>(
      ew1, eb1, ew2, eb2, fw1, fb1, fw2, fb2,
      hw1, hb1, hw2, hb2, gw1, gb1, gw2, gb2,
      pw1, pb1, pw2, pb2, tabs, ctr);

  sde_scan<<<NBLK, 64, 0, stream>>>(
      xs, ts, noise_std, eps0, dW, qw, qb,
      fw1, fb1, fw2, fb2, hw1, hb1, hw2, hb2,
      gw1, gb1, gw2, gb2, pw1, pb1, pw2, pb2,
      pz0_mean, pz0_logstd, tabs, ctr, partA, partB, out);
}

// Round 10
// 170.443 us; speedup vs baseline: 44.8392x; 18.7875x over previous
//
#include <hip/hip_runtime.h>
#include <math.h>

// LatentSDE (L=C=D=1, H=64), all nets tabulated, thread-per-b recurrence.
// R7 vs R9 falsified the memory theory (global 3.30ms == LDS 3.26ms): the
// cost was the exact-MLP OOB fallback -- z grows EXPONENTIALLY (dt=1), so
// late steps have |z| >> 128 and every wave serializes through 4x64 softplus.
// Fix: two-tier z-tables in LDS. Tier1 = R9's verified +-128 grids;
// tier2 = +-8192, dz=16 (f/h/g/p near-linear out there, curvature <=1e-5).
// Precise fallback only for |z|>8192 (~never). 90KB static LDS, 32x256.

#define B_SZ 8192
#define T_SZ 128
#define NBLK 32

// tier1 f: z in [-128,128], dz=1/8 (2048 intervals, 2049 float4)
// tier1 hgp: z in [-128,128], dz=1/4 (1024 intervals, 1025 float4)
// tier2 f & hgp: z in [-8192,8192], dz=16 (1024 intervals, 1025 float4 each)
// enc: x in [-8,8], dx=1/64 (1024 float2 pairs)

// float offsets (16B aligned)
#define FQ1_OFF  0                // 2049*4 = 8196
#define HGP1_OFF 8196             // 1025*4 = 4100
#define FQ2_OFF  12296            // 1025*4 = 4100
#define HGP2_OFF 16396            // 1025*4 = 4100
#define ET2_OFF  20496            // 1024*2 = 2048
#define TAB_FLOATS 22544          // 90,176 B
// float4 indices
#define FQ1_I  0
#define HGP1_I 2049
#define FQ2_I  3074
#define HGP2_I 4099

#define NF1_BUILD 2049
#define NH1_BUILD 1025
#define NF2_BUILD 1025
#define NH2_BUILD 1025
#define NE_BUILD  1024
#define NBUILD (NF1_BUILD+NH1_BUILD+NF2_BUILD+NH2_BUILD+NE_BUILD)  // 6148

#define NXI 1024
#define XSF 64.0f
#define XOF 512.0f

#if __has_builtin(__builtin_amdgcn_rcpf)
#define RCPF(x) __builtin_amdgcn_rcpf(x)
#else
#define RCPF(x) (1.0f / (x))
#endif
#if __has_builtin(__builtin_amdgcn_sqrtf)
#define SQRTF(x) __builtin_amdgcn_sqrtf(x)
#else
#define SQRTF(x) sqrtf(x)
#endif

__device__ __forceinline__ float sp_precise(float a) {
  return fmaxf(a, 0.0f) + log1pf(expf(-fabsf(a)));
}

// ---------------- build: exact evals into global tables ----------------
__global__ __launch_bounds__(256) void build_tabs(
    const float* __restrict__ ew1, const float* __restrict__ eb1,
    const float* __restrict__ ew2, const float* __restrict__ eb2,
    const float* __restrict__ fw1, const float* __restrict__ fb1,
    const float* __restrict__ fw2, const float* __restrict__ fb2,
    const float* __restrict__ hw1, const float* __restrict__ hb1,
    const float* __restrict__ hw2, const float* __restrict__ hb2,
    const float* __restrict__ gw1, const float* __restrict__ gb1,
    const float* __restrict__ gw2, const float* __restrict__ gb2,
    const float* __restrict__ pw1, const float* __restrict__ pb1,
    const float* __restrict__ pw2, const float* __restrict__ pb2,
    float* __restrict__ tabs, int* __restrict__ ctr)
{
  const int gid = blockIdx.x * 256 + threadIdx.x;
  if (gid == 0) *ctr = 0;

  auto fquad = [&](float z, int idx4) {
    float s0 = 0.f, s1 = 0.f, s2 = 0.f, s3 = 0.f;
    for (int j = 0; j < 64; ++j) {
      const float az = fmaf(z, fw1[j], fb1[j]);
      const float wc = fw1[64 + j], w2 = fw2[j];
      s0 = fmaf(sp_precise(fmaf(-3.0f, wc, az)), w2, s0);
      s1 = fmaf(sp_precise(fmaf(-1.0f, wc, az)), w2, s1);
      s2 = fmaf(sp_precise(fmaf( 1.0f, wc, az)), w2, s2);
      s3 = fmaf(sp_precise(fmaf( 3.0f, wc, az)), w2, s3);
    }
    const float fb = fb2[0];
    ((float4*)tabs)[idx4] = make_float4(s0 + fb, s1 + fb, s2 + fb, s3 + fb);
  };
  auto hgp = [&](float z, int idx4) {
    float sh = 0.f, sg = 0.f, sp = 0.f;
    for (int j = 0; j < 64; ++j) {
      sh = fmaf(sp_precise(fmaf(z, hw1[j], hb1[j])), hw2[j], sh);
      sg = fmaf(sp_precise(fmaf(z, gw1[j], gb1[j])), gw2[j], sg);
      sp = fmaf(sp_precise(fmaf(z, pw1[j], pb1[j])), pw2[j], sp);
    }
    ((float4*)tabs)[idx4] = make_float4(
        sh + hb2[0],
        1.0f / (1.0f + expf(-(sg + gb2[0]))),
        sp + pb2[0], 0.0f);
  };

  if (gid < NF1_BUILD) {
    fquad(-128.0f + (float)gid * 0.125f, FQ1_I + gid);
  } else if (gid < NF1_BUILD + NH1_BUILD) {
    const int i = gid - NF1_BUILD;
    hgp(-128.0f + (float)i * 0.25f, HGP1_I + i);
  } else if (gid < NF1_BUILD + NH1_BUILD + NF2_BUILD) {
    const int i = gid - NF1_BUILD - NH1_BUILD;
    fquad(-8192.0f + (float)i * 16.0f, FQ2_I + i);
  } else if (gid < NF1_BUILD + NH1_BUILD + NF2_BUILD + NH2_BUILD) {
    const int i = gid - NF1_BUILD - NH1_BUILD - NF2_BUILD;
    hgp(-8192.0f + (float)i * 16.0f, HGP2_I + i);
  } else if (gid < NBUILD) {
    const int i = gid - NF1_BUILD - NH1_BUILD - NF2_BUILD - NH2_BUILD;
    const float x0 = -8.0f + (float)i * (1.0f / 64.0f);
    const float x1 = x0 + (1.0f / 64.0f);
    float s0 = 0.f, s1 = 0.f;
    for (int j = 0; j < 64; ++j) {
      const float w = ew1[j], bb = eb1[j], w2 = ew2[j];
      s0 = fmaf(sp_precise(fmaf(x0, w, bb)), w2, s0);
      s1 = fmaf(sp_precise(fmaf(x1, w, bb)), w2, s1);
    }
    const float eb = eb2[0];
    ((float2*)(tabs + ET2_OFF))[i] = make_float2(s0 + eb, s1 + eb);
  }
}

// ---------------- scan: thread-per-b, two-tier LDS tables ----------------
__global__ __launch_bounds__(256) void sde_scan(
    const float* __restrict__ xs, const float* __restrict__ ts,
    const float* __restrict__ noise_std, const float* __restrict__ eps0,
    const float* __restrict__ dW,
    const float* __restrict__ qw,  const float* __restrict__ qb,
    const float* __restrict__ fw1, const float* __restrict__ fb1,
    const float* __restrict__ fw2, const float* __restrict__ fb2,
    const float* __restrict__ hw1, const float* __restrict__ hb1,
    const float* __restrict__ hw2, const float* __restrict__ hb2,
    const float* __restrict__ gw1, const float* __restrict__ gb1,
    const float* __restrict__ gw2, const float* __restrict__ gb2,
    const float* __restrict__ pw1, const float* __restrict__ pb1,
    const float* __restrict__ pw2, const float* __restrict__ pb2,
    const float* __restrict__ pz0_mean, const float* __restrict__ pz0_logstd,
    const float* __restrict__ tabsrc,
    int* __restrict__ ctr, float* __restrict__ partA, float* __restrict__ partB,
    float* __restrict__ out)
{
  __shared__ __align__(16) float tab[TAB_FLOATS];
  __shared__ float la[256], lb[256];
  __shared__ int lastflag;

  const int tid = threadIdx.x;
  const int b   = blockIdx.x * 256 + tid;

  { // stage all tables (float4-wise)
    const float4* s4 = (const float4*)tabsrc;
    float4* d4 = (float4*)tab;
    for (int i = tid; i < TAB_FLOATS / 4; i += 256) d4[i] = s4[i];
  }
  __syncthreads();

  const float4* tab4 = (const float4*)tab;
  const float2* et2  = (const float2*)(tab + ET2_OFF);

  const float fb2s = fb2[0], hb2s = hb2[0], gb2s = gb2[0], pb2s = pb2[0];
  const float qw0 = qw[0], qw1 = qw[1], qb0 = qb[0], qb1 = qb[1];
  const float ns = noise_std[0];
  const float inv_ns = 1.0f / ns;
  const float nh_i2 = -0.5f * inv_ns * inv_ns;
  const float pm = pz0_mean[0], pls = pz0_logstd[0];

  auto einterp = [&](float x) {
    const float s = fmaf(x, XSF, XOF);
    const float sc = fminf(fmaxf(s, 0.0f), (float)(NXI - 1));
    const int i = (int)sc;
    const float fr = s - (float)i;
    const float2 e = et2[i];
    return fmaf(fr, e.y - e.x, e.x);
  };
  auto lagr = [&](float c) {    // cubic Lagrange, nodes {-3,-1,1,3}
    const float c2 = c * c;
    const float p1 = c2 - 1.0f, p3 = c2 - 9.0f;
    return make_float4(p1 * (c - 3.0f) * (-1.0f / 48.0f),
                       p3 * (c - 1.0f) * ( 1.0f / 16.0f),
                       p3 * (c + 1.0f) * (-1.0f / 16.0f),
                       p1 * (c + 3.0f) * ( 1.0f / 48.0f));
  };
  auto hgp_exact = [&](float z, float& hv, float& gv, float& pv) {
    float sh = 0.f, sg = 0.f, sp = 0.f;
    for (int j = 0; j < 64; ++j) {
      sh = fmaf(sp_precise(fmaf(z, hw1[j], hb1[j])), hw2[j], sh);
      sg = fmaf(sp_precise(fmaf(z, gw1[j], gb1[j])), gw2[j], sg);
      sp = fmaf(sp_precise(fmaf(z, pw1[j], pb1[j])), pw2[j], sp);
    }
    hv = sh + hb2s;
    gv = 1.0f / (1.0f + expf(-(sg + gb2s)));
    pv = sp + pb2s;
  };
  auto f_exact = [&](float z, float c) {
    float s = 0.f;
    for (int j = 0; j < 64; ++j)
      s = fmaf(sp_precise(fmaf(z, fw1[j], fmaf(c, fw1[64 + j], fb1[j]))), fw2[j], s);
    return s + fb2s;
  };

  // two-tier index: fills f-idx/frac and hgp-idx/frac (+ in-range flag)
  auto zidx = [&](float z, int& fqi, float& fqf, int& hgi, float& hgf, bool& inr) {
    const float s1 = fmaf(z, 8.0f, 1024.0f);        // tier1 f grid
    const float s2 = fmaf(z, 0.0625f, 512.0f);      // tier2 grid (dz=16)
    const bool t1 = (s1 >= 0.0f) && (s1 <= 2048.0f);
    const bool t2 = (s2 >= 0.0f) && (s2 <= 1024.0f);
    inr = t1 || t2;
    const float sf = t1 ? s1 : fminf(fmaxf(s2, 0.0f), 1024.0f);
    int fi = min((int)sf, t1 ? 2047 : 1023);
    fqi = (t1 ? FQ1_I : FQ2_I) + fi;
    fqf = sf - (float)fi;
    const float sh = t1 ? fmaf(z, 4.0f, 512.0f) : sf;
    int hi = min((int)sh, 1023);
    hgi = (t1 ? HGP1_I : HGP2_I) + hi;
    hgf = sh - (float)hi;
  };

  // ---- prologue ----
  const float x0 = xs[b];
  float x1 = xs[B_SZ + b];
  float x2 = xs[2 * B_SZ + b];
  const float c0v = einterp(x0);
  float c_cur = einterp(x1);
  float c_nxt = einterp(x2);
  const float qm  = fmaf(c0v, qw0, qb0);
  const float qls = fmaf(c0v, qw1, qb1);
  float z = fmaf(__expf(qls), eps0[b], qm);
  const float dqm = qm - pm;
  const float kl = (pls - qls)
                 + (__expf(2.0f * qls) + dqm * dqm) * (0.5f * __expf(-2.0f * pls))
                 - 0.5f;

  bool zin; int fqi, hgi; float fqf, hgf;
  float4 q0, q1; float hv, gv, pv;
  zidx(z, fqi, fqf, hgi, hgf, zin);
  q0 = tab4[fqi]; q1 = tab4[fqi + 1];
  {
    const float4 a = tab4[hgi], bq = tab4[hgi + 1];
    if (zin) {
      hv = fmaf(hgf, bq.x - a.x, a.x);
      gv = fmaf(hgf, bq.y - a.y, a.y);
      pv = fmaf(hgf, bq.z - a.z, a.z);
    } else {
      hgp_exact(z, hv, gv, pv);
    }
  }
  float lp_sum; { const float d = x0 - pv; lp_sum = nh_i2 * d * d; }
  float lr_sum = 0.0f;
  float dw_cur = dW[b];
  float dw_n1  = dW[B_SZ + b];
  float4 L = lagr(c_cur);
  bool cin = fabsf(c_cur) <= 3.0f;

  // ---- Euler-Maruyama scan ----
  for (int k = 0; k < T_SZ - 1; ++k) {
    const int   i3    = (k + 3 < T_SZ) ? (k + 3) : (T_SZ - 1);
    const float x3    = xs[i3 * B_SZ + b];
    const float dw_n2 = (k + 2 < T_SZ - 1) ? dW[(k + 2) * B_SZ + b] : 0.0f;
    const float dt    = ts[k + 1] - ts[k];
    const float sq    = SQRTF(dt);

    // f(z, c_cur): z-lerp of 4 c-nodes then cubic in c
    float fv;
    if (zin && cin) {
      const float n0 = fmaf(fqf, q1.x - q0.x, q0.x);
      const float n1 = fmaf(fqf, q1.y - q0.y, q0.y);
      const float n2 = fmaf(fqf, q1.z - q0.z, q0.z);
      const float n3 = fmaf(fqf, q1.w - q0.w, q0.w);
      fv = n0 * L.x + n1 * L.y + n2 * L.z + n3 * L.w;
    } else {
      fv = f_exact(z, c_cur);
    }

    const float gvs = fmaxf(gv, 1e-6f);
    const float uu = (fv - hv) * RCPF(gvs);
    lr_sum = fmaf((0.5f * dt) * uu, uu, lr_sum);
    z = fmaf(gvs * dw_cur, sq, fmaf(fv, dt, z));

    // re-index at new z; issue all 4 gathers together
    zidx(z, fqi, fqf, hgi, hgf, zin);
    q0 = tab4[fqi]; q1 = tab4[fqi + 1];
    const float4 a = tab4[hgi], bq = tab4[hgi + 1];
    if (zin) {
      hv = fmaf(hgf, bq.x - a.x, a.x);
      gv = fmaf(hgf, bq.y - a.y, a.y);
      pv = fmaf(hgf, bq.z - a.z, a.z);
    } else {
      hgp_exact(z, hv, gv, pv);
    }

    // projector likelihood at t=k+1
    const float d = x1 - pv;
    lp_sum = fmaf(nh_i2 * d, d, lp_sum);

    // advance off-chain pipelines
    c_cur = c_nxt; L = lagr(c_cur); cin = fabsf(c_cur) <= 3.0f;
    c_nxt = einterp(x3);
    x1 = x2; x2 = x3;
    dw_cur = dw_n1; dw_n1 = dw_n2;
  }

  // ---- fused deterministic reduction ----
  la[tid] = lp_sum; lb[tid] = kl + lr_sum;
  __syncthreads();
  for (int s = 128; s > 0; s >>= 1) {
    if (tid < s) { la[tid] += la[tid + s]; lb[tid] += lb[tid + s]; }
    __syncthreads();
  }
  if (tid == 0) {
    partA[blockIdx.x] = la[0]; partB[blockIdx.x] = lb[0];
    __threadfence();
    lastflag = (atomicAdd(ctr, 1) == NBLK - 1) ? 1 : 0;
  }
  __syncthreads();
  if (lastflag) {
    __threadfence();
    la[tid] = (tid < NBLK) ? partA[tid] : 0.0f;
    lb[tid] = (tid < NBLK) ? partB[tid] : 0.0f;
    __syncthreads();
    for (int s = 128; s > 0; s >>= 1) {
      if (tid < s) { la[tid] += la[tid + s]; lb[tid] += lb[tid + s]; }
      __syncthreads();
    }
    if (tid == 0) {
      out[0] = la[0] / (float)B_SZ
             + (float)T_SZ * (-__logf(ns) - 0.9189385332046727f);
      out[1] = lb[0] / (float)B_SZ;
    }
  }
}

extern "C" void kernel_launch(void* const* d_in, const int* in_sizes, int n_in,
                              void* d_out, int out_size, void* d_ws, size_t ws_size,
                              hipStream_t stream) {
  const float* xs        = (const float*)d_in[0];
  const float* ts        = (const float*)d_in[1];
  const float* noise_std = (const float*)d_in[2];
  const float* eps0      = (const float*)d_in[3];
  const float* dW        = (const float*)d_in[4];
  const float* ew1 = (const float*)d_in[5];
  const float* eb1 = (const float*)d_in[6];
  const float* ew2 = (const float*)d_in[7];
  const float* eb2 = (const float*)d_in[8];
  const float* qw  = (const float*)d_in[9];
  const float* qb  = (const float*)d_in[10];
  const float* fw1 = (const float*)d_in[11];
  const float* fb1 = (const float*)d_in[12];
  const float* fw2 = (const float*)d_in[13];
  const float* fb2 = (const float*)d_in[14];
  const float* hw1 = (const float*)d_in[15];
  const float* hb1 = (const float*)d_in[16];
  const float* hw2 = (const float*)d_in[17];
  const float* hb2 = (const float*)d_in[18];
  const float* gw1 = (const float*)d_in[19];
  const float* gb1 = (const float*)d_in[20];
  const float* gw2 = (const float*)d_in[21];
  const float* gb2 = (const float*)d_in[22];
  const float* pw1 = (const float*)d_in[23];
  const float* pb1 = (const float*)d_in[24];
  const float* pw2 = (const float*)d_in[25];
  const float* pb2 = (const float*)d_in[26];
  const float* pz0_mean   = (const float*)d_in[27];
  const float* pz0_logstd = (const float*)d_in[28];
  float* out = (float*)d_out;

  float* tabs  = (float*)d_ws;                  // [TAB_FLOATS]
  int*   ctr   = (int*)(tabs + TAB_FLOATS);     // [1] (+pad)
  float* partA = tabs + TAB_FLOATS + 4;         // [NBLK]
  float* partB = partA + NBLK;                  // [NBLK]

  build_tabs<<<(NBUILD + 255) / 256, 256, 0, stream>>>(
      ew1, eb1, ew2, eb2, fw1, fb1, fw2, fb2,
      hw1, hb1, hw2, hb2, gw1, gb1, gw2, gb2,
      pw1, pb1, pw2, pb2, tabs, ctr);

  sde_scan<<<NBLK, 256, 0, stream>>>(
      xs, ts, noise_std, eps0, dW, qw, qb,
      fw1, fb1, fw2, fb2, hw1, hb1, hw2, hb2,
      gw1, gb1, gw2, gb2, pw1, pb1, pw2, pb2,
      pz0_mean, pz0_logstd, tabs, ctr, partA, partB, out);
}

// Round 11
// 74.096 us; speedup vs baseline: 103.1431x; 2.3003x over previous
//
#include <hip/hip_runtime.h>
#include <math.h>

// LatentSDE (L=C=D=1, H=64), all nets tabulated, thread-per-b recurrence.
// R10 result: two-tier z-table (+-128 dz=1/8, +-8192 dz=16) killed the OOB
// fallback -> absmax 0.0, scan ~45us. New bottleneck was build_tabs (113us,
// serial 64-unit loops). R11: wave-per-entry build (lane=unit, shfl reduce),
// and scan at 16x512 (2 waves/SIMD) to interleave the latency chain.

#define B_SZ 8192
#define T_SZ 128
#define NBLK 16                  // scan blocks (512 thr each)

// float offsets (16B aligned) -- layout identical to R10 (verified)
#define FQ1_OFF  0                // 2049*4 = 8196
#define HGP1_OFF 8196             // 1025*4 = 4100
#define FQ2_OFF  12296            // 1025*4 = 4100
#define HGP2_OFF 16396            // 1025*4 = 4100
#define ET2_OFF  20496            // 1024*2 = 2048
#define TAB_FLOATS 22544          // 90,176 B
// float4 indices
#define FQ1_I  0
#define HGP1_I 2049
#define FQ2_I  3074
#define HGP2_I 4099

#define NF1 2049
#define NH1 1025
#define NF2 1025
#define NH2 1025
#define NEE 1024
#define NENT (NF1+NH1+NF2+NH2+NEE)   // 6148 entries, one wave each

#define NXI 1024
#define XSF 64.0f
#define XOF 512.0f

#if __has_builtin(__builtin_amdgcn_rcpf)
#define RCPF(x) __builtin_amdgcn_rcpf(x)
#else
#define RCPF(x) (1.0f / (x))
#endif
#if __has_builtin(__builtin_amdgcn_sqrtf)
#define SQRTF(x) __builtin_amdgcn_sqrtf(x)
#else
#define SQRTF(x) sqrtf(x)
#endif

__device__ __forceinline__ float sp_precise(float a) {
  return fmaxf(a, 0.0f) + log1pf(expf(-fabsf(a)));
}
__device__ __forceinline__ float wsum64(float v) {
  #pragma unroll
  for (int m = 1; m <= 32; m <<= 1) v += __shfl_xor(v, m);
  return v;
}

// ---------------- build: one wave per table entry ----------------
__global__ __launch_bounds__(256) void build_tabs(
    const float* __restrict__ ew1, const float* __restrict__ eb1,
    const float* __restrict__ ew2, const float* __restrict__ eb2,
    const float* __restrict__ fw1, const float* __restrict__ fb1,
    const float* __restrict__ fw2, const float* __restrict__ fb2,
    const float* __restrict__ hw1, const float* __restrict__ hb1,
    const float* __restrict__ hw2, const float* __restrict__ hb2,
    const float* __restrict__ gw1, const float* __restrict__ gb1,
    const float* __restrict__ gw2, const float* __restrict__ gb2,
    const float* __restrict__ pw1, const float* __restrict__ pb1,
    const float* __restrict__ pw2, const float* __restrict__ pb2,
    float* __restrict__ tabs, int* __restrict__ ctr)
{
  const int gtid = blockIdx.x * 256 + threadIdx.x;
  if (gtid == 0) *ctr = 0;
  const int ent  = gtid >> 6;          // wave id == entry id
  const int lane = threadIdx.x & 63;
  if (ent >= NENT) return;

  if (ent < NF1 + NH1 + NF2 + NH2) {
    // z-table entry
    bool isF; float z; int idx4;
    if (ent < NF1)                { isF = true;  z = -128.0f + (float)ent * 0.125f;            idx4 = FQ1_I + ent; }
    else if (ent < NF1+NH1)       { isF = false; z = -128.0f + (float)(ent-NF1) * 0.25f;       idx4 = HGP1_I + (ent-NF1); }
    else if (ent < NF1+NH1+NF2)   { isF = true;  z = -8192.0f + (float)(ent-NF1-NH1) * 16.0f;  idx4 = FQ2_I + (ent-NF1-NH1); }
    else                          { isF = false; z = -8192.0f + (float)(ent-NF1-NH1-NF2) * 16.0f; idx4 = HGP2_I + (ent-NF1-NH1-NF2); }

    if (isF) {   // f at c-nodes {-3,-1,1,3}; lane = unit
      const float az = fmaf(z, fw1[lane], fb1[lane]);
      const float wc = fw1[64 + lane], w2 = fw2[lane];
      float s0 = sp_precise(fmaf(-3.0f, wc, az)) * w2;
      float s1 = sp_precise(fmaf(-1.0f, wc, az)) * w2;
      float s2 = sp_precise(fmaf( 1.0f, wc, az)) * w2;
      float s3 = sp_precise(fmaf( 3.0f, wc, az)) * w2;
      s0 = wsum64(s0); s1 = wsum64(s1); s2 = wsum64(s2); s3 = wsum64(s3);
      if (lane == 0) {
        const float fb = fb2[0];
        ((float4*)tabs)[idx4] = make_float4(s0 + fb, s1 + fb, s2 + fb, s3 + fb);
      }
    } else {     // h, g, p
      float sh = sp_precise(fmaf(z, hw1[lane], hb1[lane])) * hw2[lane];
      float sg = sp_precise(fmaf(z, gw1[lane], gb1[lane])) * gw2[lane];
      float sp = sp_precise(fmaf(z, pw1[lane], pb1[lane])) * pw2[lane];
      sh = wsum64(sh); sg = wsum64(sg); sp = wsum64(sp);
      if (lane == 0) {
        ((float4*)tabs)[idx4] = make_float4(
            sh + hb2[0],
            1.0f / (1.0f + expf(-(sg + gb2[0]))),
            sp + pb2[0], 0.0f);
      }
    }
  } else {
    // encoder pair entry
    const int i = ent - (NF1 + NH1 + NF2 + NH2);
    const float x0 = -8.0f + (float)i * (1.0f / 64.0f);
    const float x1 = x0 + (1.0f / 64.0f);
    const float w = ew1[lane], bb = eb1[lane], w2 = ew2[lane];
    float s0 = sp_precise(fmaf(x0, w, bb)) * w2;
    float s1 = sp_precise(fmaf(x1, w, bb)) * w2;
    s0 = wsum64(s0); s1 = wsum64(s1);
    if (lane == 0) {
      const float eb = eb2[0];
      ((float2*)(tabs + ET2_OFF))[i] = make_float2(s0 + eb, s1 + eb);
    }
  }
}

// ---------------- scan: thread-per-b, two-tier LDS tables ----------------
__global__ __launch_bounds__(512) void sde_scan(
    const float* __restrict__ xs, const float* __restrict__ ts,
    const float* __restrict__ noise_std, const float* __restrict__ eps0,
    const float* __restrict__ dW,
    const float* __restrict__ qw,  const float* __restrict__ qb,
    const float* __restrict__ fw1, const float* __restrict__ fb1,
    const float* __restrict__ fw2, const float* __restrict__ fb2,
    const float* __restrict__ hw1, const float* __restrict__ hb1,
    const float* __restrict__ hw2, const float* __restrict__ hb2,
    const float* __restrict__ gw1, const float* __restrict__ gb1,
    const float* __restrict__ gw2, const float* __restrict__ gb2,
    const float* __restrict__ pw1, const float* __restrict__ pb1,
    const float* __restrict__ pw2, const float* __restrict__ pb2,
    const float* __restrict__ pz0_mean, const float* __restrict__ pz0_logstd,
    const float* __restrict__ tabsrc,
    int* __restrict__ ctr, float* __restrict__ partA, float* __restrict__ partB,
    float* __restrict__ out)
{
  __shared__ __align__(16) float tab[TAB_FLOATS];
  __shared__ float la[512], lb[512];
  __shared__ int lastflag;

  const int tid = threadIdx.x;
  const int b   = blockIdx.x * 512 + tid;

  { // stage all tables (float4-wise)
    const float4* s4 = (const float4*)tabsrc;
    float4* d4 = (float4*)tab;
    for (int i = tid; i < TAB_FLOATS / 4; i += 512) d4[i] = s4[i];
  }
  __syncthreads();

  const float4* tab4 = (const float4*)tab;
  const float2* et2  = (const float2*)(tab + ET2_OFF);

  const float fb2s = fb2[0], hb2s = hb2[0], gb2s = gb2[0], pb2s = pb2[0];
  const float qw0 = qw[0], qw1 = qw[1], qb0 = qb[0], qb1 = qb[1];
  const float ns = noise_std[0];
  const float inv_ns = 1.0f / ns;
  const float nh_i2 = -0.5f * inv_ns * inv_ns;
  const float pm = pz0_mean[0], pls = pz0_logstd[0];

  auto einterp = [&](float x) {
    const float s = fmaf(x, XSF, XOF);
    const float sc = fminf(fmaxf(s, 0.0f), (float)(NXI - 1));
    const int i = (int)sc;
    const float fr = s - (float)i;
    const float2 e = et2[i];
    return fmaf(fr, e.y - e.x, e.x);
  };
  auto lagr = [&](float c) {    // cubic Lagrange, nodes {-3,-1,1,3}
    const float c2 = c * c;
    const float p1 = c2 - 1.0f, p3 = c2 - 9.0f;
    return make_float4(p1 * (c - 3.0f) * (-1.0f / 48.0f),
                       p3 * (c - 1.0f) * ( 1.0f / 16.0f),
                       p3 * (c + 1.0f) * (-1.0f / 16.0f),
                       p1 * (c + 3.0f) * ( 1.0f / 48.0f));
  };
  auto hgp_exact = [&](float z, float& hv, float& gv, float& pv) {
    float sh = 0.f, sg = 0.f, sp = 0.f;
    for (int j = 0; j < 64; ++j) {
      sh = fmaf(sp_precise(fmaf(z, hw1[j], hb1[j])), hw2[j], sh);
      sg = fmaf(sp_precise(fmaf(z, gw1[j], gb1[j])), gw2[j], sg);
      sp = fmaf(sp_precise(fmaf(z, pw1[j], pb1[j])), pw2[j], sp);
    }
    hv = sh + hb2s;
    gv = 1.0f / (1.0f + expf(-(sg + gb2s)));
    pv = sp + pb2s;
  };
  auto f_exact = [&](float z, float c) {
    float s = 0.f;
    for (int j = 0; j < 64; ++j)
      s = fmaf(sp_precise(fmaf(z, fw1[j], fmaf(c, fw1[64 + j], fb1[j]))), fw2[j], s);
    return s + fb2s;
  };

  // two-tier index (R10-verified)
  auto zidx = [&](float z, int& fqi, float& fqf, int& hgi, float& hgf, bool& inr) {
    const float s1 = fmaf(z, 8.0f, 1024.0f);        // tier1 f grid
    const float s2 = fmaf(z, 0.0625f, 512.0f);      // tier2 grid (dz=16)
    const bool t1 = (s1 >= 0.0f) && (s1 <= 2048.0f);
    const bool t2 = (s2 >= 0.0f) && (s2 <= 1024.0f);
    inr = t1 || t2;
    const float sf = t1 ? s1 : fminf(fmaxf(s2, 0.0f), 1024.0f);
    int fi = min((int)sf, t1 ? 2047 : 1023);
    fqi = (t1 ? FQ1_I : FQ2_I) + fi;
    fqf = sf - (float)fi;
    const float sh = t1 ? fmaf(z, 4.0f, 512.0f) : sf;
    int hi = min((int)sh, 1023);
    hgi = (t1 ? HGP1_I : HGP2_I) + hi;
    hgf = sh - (float)hi;
  };

  // ---- prologue ----
  const float x0 = xs[b];
  float x1 = xs[B_SZ + b];
  float x2 = xs[2 * B_SZ + b];
  const float c0v = einterp(x0);
  float c_cur = einterp(x1);
  float c_nxt = einterp(x2);
  const float qm  = fmaf(c0v, qw0, qb0);
  const float qls = fmaf(c0v, qw1, qb1);
  float z = fmaf(__expf(qls), eps0[b], qm);
  const float dqm = qm - pm;
  const float kl = (pls - qls)
                 + (__expf(2.0f * qls) + dqm * dqm) * (0.5f * __expf(-2.0f * pls))
                 - 0.5f;

  bool zin; int fqi, hgi; float fqf, hgf;
  float4 q0, q1; float hv, gv, pv;
  zidx(z, fqi, fqf, hgi, hgf, zin);
  q0 = tab4[fqi]; q1 = tab4[fqi + 1];
  {
    const float4 a = tab4[hgi], bq = tab4[hgi + 1];
    if (zin) {
      hv = fmaf(hgf, bq.x - a.x, a.x);
      gv = fmaf(hgf, bq.y - a.y, a.y);
      pv = fmaf(hgf, bq.z - a.z, a.z);
    } else {
      hgp_exact(z, hv, gv, pv);
    }
  }
  float lp_sum; { const float d = x0 - pv; lp_sum = nh_i2 * d * d; }
  float lr_sum = 0.0f;
  float dw_cur = dW[b];
  float dw_n1  = dW[B_SZ + b];
  float4 L = lagr(c_cur);
  bool cin = fabsf(c_cur) <= 3.0f;

  // ---- Euler-Maruyama scan ----
  for (int k = 0; k < T_SZ - 1; ++k) {
    const int   i3    = (k + 3 < T_SZ) ? (k + 3) : (T_SZ - 1);
    const float x3    = xs[i3 * B_SZ + b];
    const float dw_n2 = (k + 2 < T_SZ - 1) ? dW[(k + 2) * B_SZ + b] : 0.0f;
    const float dt    = ts[k + 1] - ts[k];
    const float sq    = SQRTF(dt);

    // f(z, c_cur): z-lerp of 4 c-nodes then cubic in c
    float fv;
    if (zin && cin) {
      const float n0 = fmaf(fqf, q1.x - q0.x, q0.x);
      const float n1 = fmaf(fqf, q1.y - q0.y, q0.y);
      const float n2 = fmaf(fqf, q1.z - q0.z, q0.z);
      const float n3 = fmaf(fqf, q1.w - q0.w, q0.w);
      fv = n0 * L.x + n1 * L.y + n2 * L.z + n3 * L.w;
    } else {
      fv = f_exact(z, c_cur);
    }

    const float gvs = fmaxf(gv, 1e-6f);
    const float uu = (fv - hv) * RCPF(gvs);
    lr_sum = fmaf((0.5f * dt) * uu, uu, lr_sum);
    z = fmaf(gvs * dw_cur, sq, fmaf(fv, dt, z));

    // re-index at new z; issue all 4 gathers together
    zidx(z, fqi, fqf, hgi, hgf, zin);
    q0 = tab4[fqi]; q1 = tab4[fqi + 1];
    const float4 a = tab4[hgi], bq = tab4[hgi + 1];
    if (zin) {
      hv = fmaf(hgf, bq.x - a.x, a.x);
      gv = fmaf(hgf, bq.y - a.y, a.y);
      pv = fmaf(hgf, bq.z - a.z, a.z);
    } else {
      hgp_exact(z, hv, gv, pv);
    }

    // projector likelihood at t=k+1
    const float d = x1 - pv;
    lp_sum = fmaf(nh_i2 * d, d, lp_sum);

    // advance off-chain pipelines
    c_cur = c_nxt; L = lagr(c_cur); cin = fabsf(c_cur) <= 3.0f;
    c_nxt = einterp(x3);
    x1 = x2; x2 = x3;
    dw_cur = dw_n1; dw_n1 = dw_n2;
  }

  // ---- fused deterministic reduction ----
  la[tid] = lp_sum; lb[tid] = kl + lr_sum;
  __syncthreads();
  for (int s = 256; s > 0; s >>= 1) {
    if (tid < s) { la[tid] += la[tid + s]; lb[tid] += lb[tid + s]; }
    __syncthreads();
  }
  if (tid == 0) {
    partA[blockIdx.x] = la[0]; partB[blockIdx.x] = lb[0];
    __threadfence();
    lastflag = (atomicAdd(ctr, 1) == NBLK - 1) ? 1 : 0;
  }
  __syncthreads();
  if (lastflag) {
    __threadfence();
    la[tid] = (tid < NBLK) ? partA[tid] : 0.0f;
    lb[tid] = (tid < NBLK) ? partB[tid] : 0.0f;
    __syncthreads();
    for (int s = 256; s > 0; s >>= 1) {
      if (tid < s) { la[tid] += la[tid + s]; lb[tid] += lb[tid + s]; }
      __syncthreads();
    }
    if (tid == 0) {
      out[0] = la[0] / (float)B_SZ
             + (float)T_SZ * (-__logf(ns) - 0.9189385332046727f);
      out[1] = lb[0] / (float)B_SZ;
    }
  }
}

extern "C" void kernel_launch(void* const* d_in, const int* in_sizes, int n_in,
                              void* d_out, int out_size, void* d_ws, size_t ws_size,
                              hipStream_t stream) {
  const float* xs        = (const float*)d_in[0];
  const float* ts        = (const float*)d_in[1];
  const float* noise_std = (const float*)d_in[2];
  const float* eps0      = (const float*)d_in[3];
  const float* dW        = (const float*)d_in[4];
  const float* ew1 = (const float*)d_in[5];
  const float* eb1 = (const float*)d_in[6];
  const float* ew2 = (const float*)d_in[7];
  const float* eb2 = (const float*)d_in[8];
  const float* qw  = (const float*)d_in[9];
  const float* qb  = (const float*)d_in[10];
  const float* fw1 = (const float*)d_in[11];
  const float* fb1 = (const float*)d_in[12];
  const float* fw2 = (const float*)d_in[13];
  const float* fb2 = (const float*)d_in[14];
  const float* hw1 = (const float*)d_in[15];
  const float* hb1 = (const float*)d_in[16];
  const float* hw2 = (const float*)d_in[17];
  const float* hb2 = (const float*)d_in[18];
  const float* gw1 = (const float*)d_in[19];
  const float* gb1 = (const float*)d_in[20];
  const float* gw2 = (const float*)d_in[21];
  const float* gb2 = (const float*)d_in[22];
  const float* pw1 = (const float*)d_in[23];
  const float* pb1 = (const float*)d_in[24];
  const float* pw2 = (const float*)d_in[25];
  const float* pb2 = (const float*)d_in[26];
  const float* pz0_mean   = (const float*)d_in[27];
  const float* pz0_logstd = (const float*)d_in[28];
  float* out = (float*)d_out;

  float* tabs  = (float*)d_ws;                  // [TAB_FLOATS]
  int*   ctr   = (int*)(tabs + TAB_FLOATS);     // [1] (+pad)
  float* partA = tabs + TAB_FLOATS + 4;         // [NBLK]
  float* partB = partA + NBLK;                  // [NBLK]

  build_tabs<<<(NENT * 64 + 255) / 256, 256, 0, stream>>>(
      ew1, eb1, ew2, eb2, fw1, fb1, fw2, fb2,
      hw1, hb1, hw2, hb2, gw1, gb1, gw2, gb2,
      pw1, pb1, pw2, pb2, tabs, ctr);

  sde_scan<<<NBLK, 512, 0, stream>>>(
      xs, ts, noise_std, eps0, dW, qw, qb,
      fw1, fb1, fw2, fb2, hw1, hb1, hw2, hb2,
      gw1, gb1, gw2, gb2, pw1, pb1, pw2, pb2,
      pz0_mean, pz0_logstd, tabs, ctr, partA, partB, out);
}